// Round 19
// baseline (76.069 us; speedup 1.0000x reference)
//
#include <hip/hip_runtime.h>

#define NN 10000
#define DIN 128
#define DOUT 256
#define NB 128           // CSR-build chunks (khist blocks)
#define NPREP 128        // prep blocks in khist_prep
#define PAD 192          // per-node CSR slot (max degree ~100 << 192)
#define NTILES (NN / 16) // 625 gemm blocks
static constexpr float BN_EPS = 1e-5f;

using short8 = __attribute__((ext_vector_type(8))) short;
using f32x4  = __attribute__((ext_vector_type(4))) float;

__device__ __forceinline__ unsigned short bf16r(float f) {
    unsigned int u = __float_as_uint(f);
    u += 0x7FFFu + ((u >> 16) & 1u);
    return (unsigned short)(u >> 16);
}
__device__ __forceinline__ float bf16f(unsigned short h) {
    return __uint_as_float((unsigned int)h << 16);
}
// fragment-order index for W[k][n] (K x 256), 16x16x32 MFMA B-operand.
__device__ __forceinline__ int fragidx(int k, int n) {
    return ((k >> 5) << 13) | ((n >> 4) << 9) |
           ((((k >> 3) & 3) << 4 | (n & 15)) << 3) | (k & 7);
}

// ---------------------------------------------------------------------------
// Kernel H+P: blocks 0..NB-1 = degree histogram + per-edge rank; blocks
// NB..NB+NPREP-1 = prep (x->xb bf16, W1/W2 frag-order bf16, zero stats)
// ---------------------------------------------------------------------------
__global__ __launch_bounds__(256) void khist_prep(
    const int* __restrict__ ei, ushort* __restrict__ hist_g,
    ushort* __restrict__ rank, int E,
    const float* __restrict__ x, ushort* __restrict__ xb,
    const float* __restrict__ W1, ushort* __restrict__ w1f,
    const float* __restrict__ W2, ushort* __restrict__ w2f,
    float* __restrict__ stats) {
    const int tid = threadIdx.x;
    if (blockIdx.x < NB) {
        __shared__ int hist[NN];
        for (int i = tid; i < NN; i += 256) hist[i] = 0;
        __syncthreads();
        const int chunk = (E + NB - 1) / NB;
        const int e0 = blockIdx.x * chunk;
        const int e1 = min(e0 + chunk, E);
        for (int e = e0 + tid; e < e1; e += 256) {
            rank[e] = (ushort)atomicAdd(&hist[ei[E + e]], 1);
        }
        __syncthreads();
        ushort* dst = hist_g + (size_t)blockIdx.x * NN;
        for (int i = tid; i < NN; i += 256) dst[i] = (ushort)hist[i];
    } else {
        const int pt = (blockIdx.x - NB) * 256 + tid;  // 0..32767
        if (pt < 8192) stats[pt] = 0.f;  // striped sums/sqs
        for (int i = pt; i < NN * DIN / 4; i += NPREP * 256) {
            const float4 v = reinterpret_cast<const float4*>(x)[i];
            ushort4 o;
            o.x = bf16r(v.x); o.y = bf16r(v.y);
            o.z = bf16r(v.z); o.w = bf16r(v.w);
            reinterpret_cast<ushort4*>(xb)[i] = o;
        }
        {   // W1: 128*256 = 32768, exactly one per thread
            const int k = pt >> 8, n = pt & 255;
            w1f[fragidx(k, n)] = bf16r(W1[pt]);
        }
        for (int i = pt; i < 256 * 256; i += NPREP * 256) {
            const int k = i >> 8, n = i & 255;
            w2f[fragidx(k, n)] = bf16r(W2[i]);
        }
    }
}

// ---------------------------------------------------------------------------
// Kernel Sa: in-place exclusive scan of hist_g along block axis; total[node]
// ---------------------------------------------------------------------------
__global__ __launch_bounds__(512) void kscan_a(ushort* __restrict__ hist_g,
                                               int* __restrict__ total) {
    const int node = blockIdx.x * 512 + threadIdx.x;
    if (node >= NN) return;
    int run = 0;
#pragma unroll 8
    for (int b = 0; b < NB; ++b) {
        const int v = hist_g[(size_t)b * NN + node];
        hist_g[(size_t)b * NN + node] = (ushort)run;
        run += v;
    }
    total[node] = run;
}

// ---------------------------------------------------------------------------
// Kernel F: rank-based CSR fill — NO LDS, NO atomics, pure streaming.
// ---------------------------------------------------------------------------
__global__ __launch_bounds__(256) void kfill(const int* __restrict__ ei,
                                             const ushort* __restrict__ hist_g,
                                             const ushort* __restrict__ rank,
                                             int* __restrict__ edge_src,
                                             int E) {
    const int chunk = (E + NB - 1) / NB;
    for (int e = blockIdx.x * 256 + threadIdx.x; e < E;
         e += gridDim.x * 256) {
        const int src = ei[e];
        const int dst = ei[E + e];
        const int b = e / chunk;
        const int pos = dst * PAD + (int)hist_g[(size_t)b * NN + dst]
                        + (int)rank[e];
        edge_src[pos] = src;
    }
}

// ---------------------------------------------------------------------------
// MFMA GEMM1, 512 threads. Gather: each half-wave walks its node's edge list
// as TWO interleaved 4-deep chains (front/back half) — halves the dependent
// chain length. B-fragments direct from frag-ordered w1f (barrier-free).
// ---------------------------------------------------------------------------
__global__ __launch_bounds__(512) void gemm1_k(
    const float* __restrict__ x, const ushort* __restrict__ xb,
    const int* __restrict__ total, const int* __restrict__ edge_src,
    const ushort* __restrict__ w1f, const float* __restrict__ b1,
    ushort* __restrict__ h1f, float* __restrict__ sum1,
    float* __restrict__ sq1) {
    __shared__ short a_lds[4 * 64 * 8];   // 4KB, A fragments (4 k-chunks)
    __shared__ float hrow[16 * 260];      // 16.6KB
    __shared__ float red_s[4 * 256];      // 4KB
    __shared__ float red_q[4 * 256];      // 4KB
    const int tid = threadIdx.x;
    const int w = tid >> 6, l = tid & 63;
    const int m = blockIdx.x;
    const int hw = tid >> 5, c4 = tid & 31;   // half-wave 0..15 = row
    const ushort4* xb4 = reinterpret_cast<const ushort4*>(xb);

    // ---- fused gather: one node per half-wave, two 4-deep chains ----
    const int node = m * 16 + hw;
    const int deg = total[node];
    const int beg = node * PAD;
    const int mid = beg + (deg >> 1);
    const int end = beg + deg;

    float4 aA[4], aB[4];
#pragma unroll
    for (int t = 0; t < 4; ++t) {
        aA[t] = make_float4(0.f, 0.f, 0.f, 0.f);
        aB[t] = aA[t];
    }
    int jA = beg, jB = mid;
    for (; jA + 3 < mid && jB + 3 < end; jA += 4, jB += 4) {
        int sA[4], sB[4];
#pragma unroll
        for (int t = 0; t < 4; ++t) {
            sA[t] = edge_src[jA + t];
            sB[t] = edge_src[jB + t];
        }
        ushort4 vA[4], vB[4];
#pragma unroll
        for (int t = 0; t < 4; ++t) {
            vA[t] = xb4[(size_t)sA[t] * 32 + c4];
            vB[t] = xb4[(size_t)sB[t] * 32 + c4];
        }
#pragma unroll
        for (int t = 0; t < 4; ++t) {
            aA[t].x += bf16f(vA[t].x); aA[t].y += bf16f(vA[t].y);
            aA[t].z += bf16f(vA[t].z); aA[t].w += bf16f(vA[t].w);
            aB[t].x += bf16f(vB[t].x); aB[t].y += bf16f(vB[t].y);
            aB[t].z += bf16f(vB[t].z); aB[t].w += bf16f(vB[t].w);
        }
    }
    for (; jA + 3 < mid; jA += 4) {
        int s[4];
#pragma unroll
        for (int t = 0; t < 4; ++t) s[t] = edge_src[jA + t];
        ushort4 v[4];
#pragma unroll
        for (int t = 0; t < 4; ++t) v[t] = xb4[(size_t)s[t] * 32 + c4];
#pragma unroll
        for (int t = 0; t < 4; ++t) {
            aA[t].x += bf16f(v[t].x); aA[t].y += bf16f(v[t].y);
            aA[t].z += bf16f(v[t].z); aA[t].w += bf16f(v[t].w);
        }
    }
    for (; jA < mid; ++jA) {
        const ushort4 v = xb4[(size_t)edge_src[jA] * 32 + c4];
        aA[0].x += bf16f(v.x); aA[0].y += bf16f(v.y);
        aA[0].z += bf16f(v.z); aA[0].w += bf16f(v.w);
    }
    for (; jB + 3 < end; jB += 4) {
        int s[4];
#pragma unroll
        for (int t = 0; t < 4; ++t) s[t] = edge_src[jB + t];
        ushort4 v[4];
#pragma unroll
        for (int t = 0; t < 4; ++t) v[t] = xb4[(size_t)s[t] * 32 + c4];
#pragma unroll
        for (int t = 0; t < 4; ++t) {
            aB[t].x += bf16f(v[t].x); aB[t].y += bf16f(v[t].y);
            aB[t].z += bf16f(v[t].z); aB[t].w += bf16f(v[t].w);
        }
    }
    for (; jB < end; ++jB) {
        const ushort4 v = xb4[(size_t)edge_src[jB] * 32 + c4];
        aB[0].x += bf16f(v.x); aB[0].y += bf16f(v.y);
        aB[0].z += bf16f(v.z); aB[0].w += bf16f(v.w);
    }
    {
        const float4 xv =
            reinterpret_cast<const float4*>(x)[(size_t)node * 32 + c4];
        ushort4 o;
        o.x = bf16r(xv.x + aA[0].x + aA[1].x + aA[2].x + aA[3].x
                         + aB[0].x + aB[1].x + aB[2].x + aB[3].x);
        o.y = bf16r(xv.y + aA[0].y + aA[1].y + aA[2].y + aA[3].y
                         + aB[0].y + aB[1].y + aB[2].y + aB[3].y);
        o.z = bf16r(xv.z + aA[0].z + aA[1].z + aA[2].z + aA[3].z
                         + aB[0].z + aB[1].z + aB[2].z + aB[3].z);
        o.w = bf16r(xv.w + aA[0].w + aA[1].w + aA[2].w + aA[3].w
                         + aB[0].w + aB[1].w + aB[2].w + aB[3].w);
        const int c = c4 >> 3, kg = (c4 >> 1) & 3, half = c4 & 1;
        *reinterpret_cast<ushort4*>(
            (char*)a_lds + c * 1024 + ((kg << 4) + hw) * 16 + half * 8) = o;
    }
    __syncthreads();

    f32x4 acc[2];
#pragma unroll
    for (int p = 0; p < 2; ++p) {
        const float b = b1[(w * 2 + p) * 16 + (l & 15)];
        acc[p] = (f32x4){b, b, b, b};
    }

    // barrier-free K-loop: B-fragments straight from global (frag-ordered)
    const short8* w1v = reinterpret_cast<const short8*>(w1f);
#pragma unroll
    for (int cc = 0; cc < 4; ++cc) {
        const short8 a = ((const short8*)a_lds)[cc * 64 + l];
#pragma unroll
        for (int p = 0; p < 2; ++p) {
            const short8 b = w1v[cc * 1024 + (w * 2 + p) * 64 + l];
            acc[p] = __builtin_amdgcn_mfma_f32_16x16x32_bf16(a, b, acc[p],
                                                             0, 0, 0);
        }
    }
    __syncthreads();

    // D -> hrow + per-row-group BN partials (each slot written exactly once)
#pragma unroll
    for (int p = 0; p < 2; ++p) {
        const int col = (w * 2 + p) * 16 + (l & 15);
        float s = 0.f, q = 0.f;
#pragma unroll
        for (int r = 0; r < 4; ++r) {
            const float v = acc[p][r];
            hrow[((l >> 4) * 4 + r) * 260 + col] = v;
            s += v;
            q += v * v;
        }
        red_s[(l >> 4) * 256 + col] = s;
        red_q[(l >> 4) * 256 + col] = q;
    }
    __syncthreads();
    if (tid < 256) {
        float s = 0.f;
#pragma unroll
        for (int g = 0; g < 4; ++g) s += red_s[g * 256 + tid];
        atomicAdd(&sum1[(m & 7) * 256 + tid], s);
    } else {
        const int col = tid - 256;
        float q = 0.f;
#pragma unroll
        for (int g = 0; g < 4; ++g) q += red_q[g * 256 + col];
        atomicAdd(&sq1[(m & 7) * 256 + col], q);
    }
    // h1f write: 512 frags (gemm2 A order), 1 per thread
    {
        const int u = tid;
        const int c2 = u >> 6, kg2 = (u >> 4) & 3, row = u & 15;
        const float* src = &hrow[row * 260 + c2 * 32 + kg2 * 8];
        short8 g;
#pragma unroll
        for (int jj = 0; jj < 8; ++jj) g[jj] = (short)bf16r(src[jj]);
        ((short8*)h1f)[m * 512 + u] = g;
    }
}

// ---------------------------------------------------------------------------
// MFMA GEMM2, 512 threads, barrier-free K-loop (B direct from w2f).
// BN1 finalize fused; h2 stored bf16; striped BN2 sums.
// ---------------------------------------------------------------------------
__global__ __launch_bounds__(512) void gemm2_k(
    const ushort* __restrict__ h1f, const float* __restrict__ sum1,
    const float* __restrict__ sq1, const float* __restrict__ gamma1,
    const float* __restrict__ beta1, const ushort* __restrict__ w2f,
    const float* __restrict__ b2, ushort* __restrict__ h2b,
    float* __restrict__ sum2, float* __restrict__ sq2) {
    __shared__ short a_lds[8 * 64 * 8];   // 8KB
    __shared__ float hrow[16 * 260];
    __shared__ float red_s[4 * 256];
    __shared__ float red_q[4 * 256];
    __shared__ float sc1[DOUT], sh1[DOUT];
    const int tid = threadIdx.x;
    const int w = tid >> 6, l = tid & 63;
    const int m = blockIdx.x;

    if (tid < 256) {   // BN1 finalize from striped sums
        float s = 0.f, q = 0.f;
#pragma unroll
        for (int i = 0; i < 8; ++i) {
            s += sum1[i * 256 + tid];
            q += sq1[i * 256 + tid];
        }
        const float nInv = 1.0f / (float)NN;
        const float mean = s * nInv;
        const float var = q * nInv - mean * mean;
        const float sc = gamma1[tid] * rsqrtf(var + BN_EPS);
        sc1[tid] = sc;
        sh1[tid] = beta1[tid] - mean * sc;
    }
    __syncthreads();

    // stage A with fused bn1+relu (coalesced 16B frag reads), 1 per thread
    {
        const int u = tid;
        const int col0 = ((u >> 6) << 5) + (((u >> 4) & 3) << 3);
        const short8 hv = ((const short8*)h1f)[m * 512 + u];
        short8 g;
#pragma unroll
        for (int jj = 0; jj < 8; ++jj) {
            const float f = bf16f((unsigned short)hv[jj]);
            const float r = fmaxf(fmaf(f, sc1[col0 + jj], sh1[col0 + jj]), 0.f);
            g[jj] = (short)bf16r(r);
        }
        ((short8*)a_lds)[u] = g;
    }
    __syncthreads();

    f32x4 acc[2];
#pragma unroll
    for (int p = 0; p < 2; ++p) {
        const float b = b2[(w * 2 + p) * 16 + (l & 15)];
        acc[p] = (f32x4){b, b, b, b};
    }

    const short8* w2v = reinterpret_cast<const short8*>(w2f);
#pragma unroll
    for (int c = 0; c < 8; ++c) {
        const short8 a = ((const short8*)a_lds)[c * 64 + l];
#pragma unroll
        for (int p = 0; p < 2; ++p) {
            const short8 b = w2v[c * 1024 + (w * 2 + p) * 64 + l];
            acc[p] = __builtin_amdgcn_mfma_f32_16x16x32_bf16(a, b, acc[p],
                                                             0, 0, 0);
        }
    }
    __syncthreads();

#pragma unroll
    for (int p = 0; p < 2; ++p) {
        const int col = (w * 2 + p) * 16 + (l & 15);
        float s = 0.f, q = 0.f;
#pragma unroll
        for (int r = 0; r < 4; ++r) {
            const float v = acc[p][r];
            hrow[((l >> 4) * 4 + r) * 260 + col] = v;
            s += v;
            q += v * v;
        }
        red_s[(l >> 4) * 256 + col] = s;
        red_q[(l >> 4) * 256 + col] = q;
    }
    __syncthreads();
    if (tid < 256) {
        float s = 0.f;
#pragma unroll
        for (int g = 0; g < 4; ++g) s += red_s[g * 256 + tid];
        atomicAdd(&sum2[(m & 7) * 256 + tid], s);
    } else {
        const int col = tid - 256;
        float q = 0.f;
#pragma unroll
        for (int g = 0; g < 4; ++g) q += red_q[g * 256 + col];
        atomicAdd(&sq2[(m & 7) * 256 + col], q);
    }
    // h2 bf16 row-major (coalesced, 16B/thread)
    {
        const int idx = tid;                      // 512 x (8 bf16)
        const int row = idx >> 5, col8 = idx & 31;
        const float* src = &hrow[row * 260 + col8 * 8];
        ushort4 lo, hi;
        lo.x = bf16r(src[0]); lo.y = bf16r(src[1]);
        lo.z = bf16r(src[2]); lo.w = bf16r(src[3]);
        hi.x = bf16r(src[4]); hi.y = bf16r(src[5]);
        hi.z = bf16r(src[6]); hi.w = bf16r(src[7]);
        reinterpret_cast<ushort4*>(h2b)[((size_t)(m * 16 + row) * 64 +
                                         col8 * 2)] = lo;
        reinterpret_cast<ushort4*>(h2b)[((size_t)(m * 16 + row) * 64 +
                                         col8 * 2 + 1)] = hi;
    }
}

// ---------------------------------------------------------------------------
// Kernel 5: out = relu(bn2(h2b)); BN2 finalize (striped) fused; bf16 input
// ---------------------------------------------------------------------------
__global__ __launch_bounds__(256) void bn_relu_out_k(
    const ushort* __restrict__ h2b, const float* __restrict__ sum2,
    const float* __restrict__ sq2, const float* __restrict__ gamma2,
    const float* __restrict__ beta2, float* __restrict__ out) {
    __shared__ float sc2[DOUT], sh2[DOUT];
    const int tid = threadIdx.x;
    {
        float s = 0.f, q = 0.f;
#pragma unroll
        for (int i = 0; i < 8; ++i) {
            s += sum2[i * 256 + tid];
            q += sq2[i * 256 + tid];
        }
        const float nInv = 1.0f / (float)NN;
        const float mean = s * nInv;
        const float var = q * nInv - mean * mean;
        const float sc = gamma2[tid] * rsqrtf(var + BN_EPS);
        sc2[tid] = sc;
        sh2[tid] = beta2[tid] - mean * sc;
    }
    __syncthreads();
#pragma unroll
    for (int i = 0; i < 4; ++i) {
        const int u = blockIdx.x * 1024 + i * 256 + tid;  // quad index
        const int k4 = u & 63;
        const ushort4 hv = reinterpret_cast<const ushort4*>(h2b)[u];
        const float4 sc = reinterpret_cast<const float4*>(sc2)[k4];
        const float4 sh = reinterpret_cast<const float4*>(sh2)[k4];
        float4 g;
        g.x = fmaxf(fmaf(bf16f(hv.x), sc.x, sh.x), 0.f);
        g.y = fmaxf(fmaf(bf16f(hv.y), sc.y, sh.y), 0.f);
        g.z = fmaxf(fmaf(bf16f(hv.z), sc.z, sh.z), 0.f);
        g.w = fmaxf(fmaf(bf16f(hv.w), sc.w, sh.w), 0.f);
        reinterpret_cast<float4*>(out)[u] = g;
    }
}

// ---------------------------------------------------------------------------
extern "C" void kernel_launch(void* const* d_in, const int* in_sizes, int n_in,
                              void* d_out, int out_size, void* d_ws,
                              size_t ws_size, hipStream_t stream) {
    const float* x      = (const float*)d_in[0];
    const int*   ei     = (const int*)d_in[1];
    const float* W1     = (const float*)d_in[2];
    const float* b1     = (const float*)d_in[3];
    const float* gamma1 = (const float*)d_in[4];
    const float* beta1  = (const float*)d_in[5];
    const float* W2     = (const float*)d_in[6];
    const float* b2     = (const float*)d_in[7];
    const float* gamma2 = (const float*)d_in[8];
    const float* beta2  = (const float*)d_in[9];
    const int E = in_sizes[1] / 2;

    char* w = (char*)d_ws;
    size_t off = 0;
    float* stats = (float*)(w + off); off += 32768;  // 8192 floats (striped)
    float* sum1 = stats + 0;
    float* sq1  = stats + 2048;
    float* sum2 = stats + 4096;
    float* sq2  = stats + 6144;
    ushort* hist_g = (ushort*)(w + off); off += (size_t)NB * NN * 2;
    ushort* rank   = (ushort*)(w + off); off += (size_t)E * 2;
    int* total    = (int*)(w + off); off += 40064;
    int* edge_src = (int*)(w + off); off += (size_t)NN * PAD * 4;
    ushort* xb    = (ushort*)(w + off); off += (size_t)NN * DIN * 2;
    ushort* w1f   = (ushort*)(w + off); off += 65536;
    ushort* w2f   = (ushort*)(w + off); off += 131072;
    ushort* h1f   = (ushort*)(w + off); off += (size_t)NN * DOUT * 2;
    ushort* h2b   = (ushort*)(w + off); off += (size_t)NN * DOUT * 2;
    float* out    = (float*)d_out;

    khist_prep<<<NB + NPREP, 256, 0, stream>>>(ei, hist_g, rank, E, x, xb,
                                               W1, w1f, W2, w2f, stats);
    kscan_a<<<20, 512, 0, stream>>>(hist_g, total);
    kfill<<<640, 256, 0, stream>>>(ei, hist_g, rank, edge_src, E);
    gemm1_k<<<NTILES, 512, 0, stream>>>(x, xb, total, edge_src, w1f, b1,
                                        h1f, sum1, sq1);
    gemm2_k<<<NTILES, 512, 0, stream>>>(h1f, sum1, sq1, gamma1, beta1, w2f,
                                        b2, h2b, sum2, sq2);
    bn_relu_out_k<<<NN * DOUT / 4 / 1024, 256, 0, stream>>>(h2b, sum2, sq2,
                                                            gamma2, beta2, out);
}

// Round 20
// 72.118 us; speedup vs baseline: 1.0548x; 1.0548x over previous
//
#include <hip/hip_runtime.h>

#define NN 10000
#define DIN 128
#define DOUT 256
#define NB 64            // CSR-build chunks (khist blocks)
#define NPREP 128        // prep blocks in khist_prep
#define PAD 192          // per-node CSR slot (max degree ~100 << 192)
#define NTILES (NN / 16) // 625 gemm blocks
static constexpr float BN_EPS = 1e-5f;

using short8 = __attribute__((ext_vector_type(8))) short;
using f32x4  = __attribute__((ext_vector_type(4))) float;

__device__ __forceinline__ unsigned short bf16r(float f) {
    unsigned int u = __float_as_uint(f);
    u += 0x7FFFu + ((u >> 16) & 1u);
    return (unsigned short)(u >> 16);
}
__device__ __forceinline__ float bf16f(unsigned short h) {
    return __uint_as_float((unsigned int)h << 16);
}
// fragment-order index for W[k][n] (K x 256), 16x16x32 MFMA B-operand.
__device__ __forceinline__ int fragidx(int k, int n) {
    return ((k >> 5) << 13) | ((n >> 4) << 9) |
           ((((k >> 3) & 3) << 4 | (n & 15)) << 3) | (k & 7);
}

// ---------------------------------------------------------------------------
// Kernel H+P: blocks 0..NB-1 = degree histogram + per-edge rank; blocks
// NB..NB+NPREP-1 = prep (x->xb bf16, W1/W2 frag-order bf16, zero stats)
// ---------------------------------------------------------------------------
__global__ __launch_bounds__(256) void khist_prep(
    const int* __restrict__ ei, ushort* __restrict__ hist_g,
    ushort* __restrict__ rank, int E,
    const float* __restrict__ x, ushort* __restrict__ xb,
    const float* __restrict__ W1, ushort* __restrict__ w1f,
    const float* __restrict__ W2, ushort* __restrict__ w2f,
    float* __restrict__ stats) {
    const int tid = threadIdx.x;
    if (blockIdx.x < NB) {
        __shared__ int hist[NN];
        for (int i = tid; i < NN; i += 256) hist[i] = 0;
        __syncthreads();
        const int chunk = (E + NB - 1) / NB;
        const int e0 = blockIdx.x * chunk;
        const int e1 = min(e0 + chunk, E);
        for (int e = e0 + tid; e < e1; e += 256) {
            rank[e] = (ushort)atomicAdd(&hist[ei[E + e]], 1);
        }
        __syncthreads();
        ushort* dst = hist_g + (size_t)blockIdx.x * NN;
        for (int i = tid; i < NN; i += 256) dst[i] = (ushort)hist[i];
    } else {
        const int pt = (blockIdx.x - NB) * 256 + tid;  // 0..32767
        if (pt < 8192) stats[pt] = 0.f;  // striped sums/sqs
        for (int i = pt; i < NN * DIN / 4; i += NPREP * 256) {
            const float4 v = reinterpret_cast<const float4*>(x)[i];
            ushort4 o;
            o.x = bf16r(v.x); o.y = bf16r(v.y);
            o.z = bf16r(v.z); o.w = bf16r(v.w);
            reinterpret_cast<ushort4*>(xb)[i] = o;
        }
        {   // W1: 128*256 = 32768, exactly one per thread
            const int k = pt >> 8, n = pt & 255;
            w1f[fragidx(k, n)] = bf16r(W1[pt]);
        }
        for (int i = pt; i < 256 * 256; i += NPREP * 256) {
            const int k = i >> 8, n = i & 255;
            w2f[fragidx(k, n)] = bf16r(W2[i]);
        }
    }
}

// ---------------------------------------------------------------------------
// Kernel Sa: in-place exclusive scan of hist_g along block axis; total[node]
// ---------------------------------------------------------------------------
__global__ __launch_bounds__(256) void kscan_a(ushort* __restrict__ hist_g,
                                               int* __restrict__ total) {
    const int node = blockIdx.x * 256 + threadIdx.x;
    if (node >= NN) return;
    int run = 0;
#pragma unroll 8
    for (int b = 0; b < NB; ++b) {
        const int v = hist_g[(size_t)b * NN + node];
        hist_g[(size_t)b * NN + node] = (ushort)run;
        run += v;
    }
    total[node] = run;
}

// ---------------------------------------------------------------------------
// Kernel F: rank-based CSR fill — NO LDS, NO atomics, pure streaming.
// ---------------------------------------------------------------------------
__global__ __launch_bounds__(256) void kfill(const int* __restrict__ ei,
                                             const ushort* __restrict__ hist_g,
                                             const ushort* __restrict__ rank,
                                             int* __restrict__ edge_src,
                                             int E) {
    const int chunk = (E + NB - 1) / NB;
    for (int e = blockIdx.x * 256 + threadIdx.x; e < E;
         e += gridDim.x * 256) {
        const int src = ei[e];
        const int dst = ei[E + e];
        const int b = e / chunk;
        const int pos = dst * PAD + (int)hist_g[(size_t)b * NN + dst]
                        + (int)rank[e];
        edge_src[pos] = src;
    }
}

// ---------------------------------------------------------------------------
// MFMA GEMM1, 512 threads. B-fragments read DIRECTLY from frag-ordered w1f
// in global (L2-resident) — no b_lds staging, no K-loop barriers.
// ---------------------------------------------------------------------------
__global__ __launch_bounds__(512) void gemm1_k(
    const float* __restrict__ x, const ushort* __restrict__ xb,
    const int* __restrict__ total, const int* __restrict__ edge_src,
    const ushort* __restrict__ w1f, const float* __restrict__ b1,
    ushort* __restrict__ h1f, float* __restrict__ sum1,
    float* __restrict__ sq1) {
    __shared__ short a_lds[4 * 64 * 8];   // 4KB, A fragments (4 k-chunks)
    __shared__ float hrow[16 * 260];      // 16.6KB
    __shared__ float red_s[4 * 256];      // 4KB
    __shared__ float red_q[4 * 256];      // 4KB
    const int tid = threadIdx.x;
    const int w = tid >> 6, l = tid & 63;
    const int m = blockIdx.x;
    const int hw = tid >> 5, c4 = tid & 31;   // half-wave 0..15 = row
    const ushort4* xb4 = reinterpret_cast<const ushort4*>(xb);

    // ---- fused gather: one node per half-wave, 4-deep unroll ----
    const int node = m * 16 + hw;
    const int beg = node * PAD, end = beg + total[node];
    float4 a0 = make_float4(0.f, 0.f, 0.f, 0.f);
    float4 a1 = a0, a2 = a0, a3 = a0;
    int j = beg;
    for (; j + 3 < end; j += 4) {
        int s[4];
#pragma unroll
        for (int t = 0; t < 4; ++t) s[t] = edge_src[j + t];
        ushort4 v[4];
#pragma unroll
        for (int t = 0; t < 4; ++t) v[t] = xb4[(size_t)s[t] * 32 + c4];
        a0.x += bf16f(v[0].x); a0.y += bf16f(v[0].y);
        a0.z += bf16f(v[0].z); a0.w += bf16f(v[0].w);
        a1.x += bf16f(v[1].x); a1.y += bf16f(v[1].y);
        a1.z += bf16f(v[1].z); a1.w += bf16f(v[1].w);
        a2.x += bf16f(v[2].x); a2.y += bf16f(v[2].y);
        a2.z += bf16f(v[2].z); a2.w += bf16f(v[2].w);
        a3.x += bf16f(v[3].x); a3.y += bf16f(v[3].y);
        a3.z += bf16f(v[3].z); a3.w += bf16f(v[3].w);
    }
    for (; j < end; ++j) {
        const ushort4 v = xb4[(size_t)edge_src[j] * 32 + c4];
        a0.x += bf16f(v.x); a0.y += bf16f(v.y);
        a0.z += bf16f(v.z); a0.w += bf16f(v.w);
    }
    {
        const float4 xv =
            reinterpret_cast<const float4*>(x)[(size_t)node * 32 + c4];
        ushort4 o;
        o.x = bf16r(xv.x + a0.x + a1.x + a2.x + a3.x);
        o.y = bf16r(xv.y + a0.y + a1.y + a2.y + a3.y);
        o.z = bf16r(xv.z + a0.z + a1.z + a2.z + a3.z);
        o.w = bf16r(xv.w + a0.w + a1.w + a2.w + a3.w);
        const int c = c4 >> 3, kg = (c4 >> 1) & 3, half = c4 & 1;
        *reinterpret_cast<ushort4*>(
            (char*)a_lds + c * 1024 + ((kg << 4) + hw) * 16 + half * 8) = o;
    }
    __syncthreads();

    f32x4 acc[2];
#pragma unroll
    for (int p = 0; p < 2; ++p) {
        const float b = b1[(w * 2 + p) * 16 + (l & 15)];
        acc[p] = (f32x4){b, b, b, b};
    }

    // barrier-free K-loop: B-fragments straight from global (frag-ordered)
    const short8* w1v = reinterpret_cast<const short8*>(w1f);
#pragma unroll
    for (int cc = 0; cc < 4; ++cc) {
        const short8 a = ((const short8*)a_lds)[cc * 64 + l];
#pragma unroll
        for (int p = 0; p < 2; ++p) {
            const short8 b = w1v[cc * 1024 + (w * 2 + p) * 64 + l];
            acc[p] = __builtin_amdgcn_mfma_f32_16x16x32_bf16(a, b, acc[p],
                                                             0, 0, 0);
        }
    }
    __syncthreads();

    // D -> hrow + per-row-group BN partials (each slot written exactly once)
#pragma unroll
    for (int p = 0; p < 2; ++p) {
        const int col = (w * 2 + p) * 16 + (l & 15);
        float s = 0.f, q = 0.f;
#pragma unroll
        for (int r = 0; r < 4; ++r) {
            const float v = acc[p][r];
            hrow[((l >> 4) * 4 + r) * 260 + col] = v;
            s += v;
            q += v * v;
        }
        red_s[(l >> 4) * 256 + col] = s;
        red_q[(l >> 4) * 256 + col] = q;
    }
    __syncthreads();
    if (tid < 256) {
        float s = 0.f;
#pragma unroll
        for (int g = 0; g < 4; ++g) s += red_s[g * 256 + tid];
        atomicAdd(&sum1[(m & 7) * 256 + tid], s);
    } else {
        const int col = tid - 256;
        float q = 0.f;
#pragma unroll
        for (int g = 0; g < 4; ++g) q += red_q[g * 256 + col];
        atomicAdd(&sq1[(m & 7) * 256 + col], q);
    }
    // h1f write: 512 frags (gemm2 A order), 1 per thread
    {
        const int u = tid;
        const int c2 = u >> 6, kg2 = (u >> 4) & 3, row = u & 15;
        const float* src = &hrow[row * 260 + c2 * 32 + kg2 * 8];
        short8 g;
#pragma unroll
        for (int jj = 0; jj < 8; ++jj) g[jj] = (short)bf16r(src[jj]);
        ((short8*)h1f)[m * 512 + u] = g;
    }
}

// ---------------------------------------------------------------------------
// MFMA GEMM2, 512 threads, barrier-free K-loop (B direct from w2f).
// BN1 finalize fused; h2 stored bf16; striped BN2 sums.
// ---------------------------------------------------------------------------
__global__ __launch_bounds__(512) void gemm2_k(
    const ushort* __restrict__ h1f, const float* __restrict__ sum1,
    const float* __restrict__ sq1, const float* __restrict__ gamma1,
    const float* __restrict__ beta1, const ushort* __restrict__ w2f,
    const float* __restrict__ b2, ushort* __restrict__ h2b,
    float* __restrict__ sum2, float* __restrict__ sq2) {
    __shared__ short a_lds[8 * 64 * 8];   // 8KB
    __shared__ float hrow[16 * 260];
    __shared__ float red_s[4 * 256];
    __shared__ float red_q[4 * 256];
    __shared__ float sc1[DOUT], sh1[DOUT];
    const int tid = threadIdx.x;
    const int w = tid >> 6, l = tid & 63;
    const int m = blockIdx.x;

    if (tid < 256) {   // BN1 finalize from striped sums
        float s = 0.f, q = 0.f;
#pragma unroll
        for (int i = 0; i < 8; ++i) {
            s += sum1[i * 256 + tid];
            q += sq1[i * 256 + tid];
        }
        const float nInv = 1.0f / (float)NN;
        const float mean = s * nInv;
        const float var = q * nInv - mean * mean;
        const float sc = gamma1[tid] * rsqrtf(var + BN_EPS);
        sc1[tid] = sc;
        sh1[tid] = beta1[tid] - mean * sc;
    }
    __syncthreads();

    // stage A with fused bn1+relu (coalesced 16B frag reads), 1 per thread
    {
        const int u = tid;
        const int col0 = ((u >> 6) << 5) + (((u >> 4) & 3) << 3);
        const short8 hv = ((const short8*)h1f)[m * 512 + u];
        short8 g;
#pragma unroll
        for (int jj = 0; jj < 8; ++jj) {
            const float f = bf16f((unsigned short)hv[jj]);
            const float r = fmaxf(fmaf(f, sc1[col0 + jj], sh1[col0 + jj]), 0.f);
            g[jj] = (short)bf16r(r);
        }
        ((short8*)a_lds)[u] = g;
    }
    __syncthreads();

    f32x4 acc[2];
#pragma unroll
    for (int p = 0; p < 2; ++p) {
        const float b = b2[(w * 2 + p) * 16 + (l & 15)];
        acc[p] = (f32x4){b, b, b, b};
    }

    const short8* w2v = reinterpret_cast<const short8*>(w2f);
#pragma unroll
    for (int c = 0; c < 8; ++c) {
        const short8 a = ((const short8*)a_lds)[c * 64 + l];
#pragma unroll
        for (int p = 0; p < 2; ++p) {
            const short8 b = w2v[c * 1024 + (w * 2 + p) * 64 + l];
            acc[p] = __builtin_amdgcn_mfma_f32_16x16x32_bf16(a, b, acc[p],
                                                             0, 0, 0);
        }
    }
    __syncthreads();

#pragma unroll
    for (int p = 0; p < 2; ++p) {
        const int col = (w * 2 + p) * 16 + (l & 15);
        float s = 0.f, q = 0.f;
#pragma unroll
        for (int r = 0; r < 4; ++r) {
            const float v = acc[p][r];
            hrow[((l >> 4) * 4 + r) * 260 + col] = v;
            s += v;
            q += v * v;
        }
        red_s[(l >> 4) * 256 + col] = s;
        red_q[(l >> 4) * 256 + col] = q;
    }
    __syncthreads();
    if (tid < 256) {
        float s = 0.f;
#pragma unroll
        for (int g = 0; g < 4; ++g) s += red_s[g * 256 + tid];
        atomicAdd(&sum2[(m & 7) * 256 + tid], s);
    } else {
        const int col = tid - 256;
        float q = 0.f;
#pragma unroll
        for (int g = 0; g < 4; ++g) q += red_q[g * 256 + col];
        atomicAdd(&sq2[(m & 7) * 256 + col], q);
    }
    // h2 bf16 row-major (coalesced, 16B/thread)
    {
        const int idx = tid;                      // 512 x (8 bf16)
        const int row = idx >> 5, col8 = idx & 31;
        const float* src = &hrow[row * 260 + col8 * 8];
        ushort4 lo, hi;
        lo.x = bf16r(src[0]); lo.y = bf16r(src[1]);
        lo.z = bf16r(src[2]); lo.w = bf16r(src[3]);
        hi.x = bf16r(src[4]); hi.y = bf16r(src[5]);
        hi.z = bf16r(src[6]); hi.w = bf16r(src[7]);
        reinterpret_cast<ushort4*>(h2b)[((size_t)(m * 16 + row) * 64 +
                                         col8 * 2)] = lo;
        reinterpret_cast<ushort4*>(h2b)[((size_t)(m * 16 + row) * 64 +
                                         col8 * 2 + 1)] = hi;
    }
}

// ---------------------------------------------------------------------------
// Kernel 5: out = relu(bn2(h2b)); BN2 finalize (striped) fused; bf16 input
// ---------------------------------------------------------------------------
__global__ __launch_bounds__(256) void bn_relu_out_k(
    const ushort* __restrict__ h2b, const float* __restrict__ sum2,
    const float* __restrict__ sq2, const float* __restrict__ gamma2,
    const float* __restrict__ beta2, float* __restrict__ out) {
    __shared__ float sc2[DOUT], sh2[DOUT];
    const int tid = threadIdx.x;
    {
        float s = 0.f, q = 0.f;
#pragma unroll
        for (int i = 0; i < 8; ++i) {
            s += sum2[i * 256 + tid];
            q += sq2[i * 256 + tid];
        }
        const float nInv = 1.0f / (float)NN;
        const float mean = s * nInv;
        const float var = q * nInv - mean * mean;
        const float sc = gamma2[tid] * rsqrtf(var + BN_EPS);
        sc2[tid] = sc;
        sh2[tid] = beta2[tid] - mean * sc;
    }
    __syncthreads();
#pragma unroll
    for (int i = 0; i < 4; ++i) {
        const int u = blockIdx.x * 1024 + i * 256 + tid;  // quad index
        const int k4 = u & 63;
        const ushort4 hv = reinterpret_cast<const ushort4*>(h2b)[u];
        const float4 sc = reinterpret_cast<const float4*>(sc2)[k4];
        const float4 sh = reinterpret_cast<const float4*>(sh2)[k4];
        float4 g;
        g.x = fmaxf(fmaf(bf16f(hv.x), sc.x, sh.x), 0.f);
        g.y = fmaxf(fmaf(bf16f(hv.y), sc.y, sh.y), 0.f);
        g.z = fmaxf(fmaf(bf16f(hv.z), sc.z, sh.z), 0.f);
        g.w = fmaxf(fmaf(bf16f(hv.w), sc.w, sh.w), 0.f);
        reinterpret_cast<float4*>(out)[u] = g;
    }
}

// ---------------------------------------------------------------------------
extern "C" void kernel_launch(void* const* d_in, const int* in_sizes, int n_in,
                              void* d_out, int out_size, void* d_ws,
                              size_t ws_size, hipStream_t stream) {
    const float* x      = (const float*)d_in[0];
    const int*   ei     = (const int*)d_in[1];
    const float* W1     = (const float*)d_in[2];
    const float* b1     = (const float*)d_in[3];
    const float* gamma1 = (const float*)d_in[4];
    const float* beta1  = (const float*)d_in[5];
    const float* W2     = (const float*)d_in[6];
    const float* b2     = (const float*)d_in[7];
    const float* gamma2 = (const float*)d_in[8];
    const float* beta2  = (const float*)d_in[9];
    const int E = in_sizes[1] / 2;

    char* w = (char*)d_ws;
    size_t off = 0;
    float* stats = (float*)(w + off); off += 32768;  // 8192 floats (striped)
    float* sum1 = stats + 0;
    float* sq1  = stats + 2048;
    float* sum2 = stats + 4096;
    float* sq2  = stats + 6144;
    ushort* hist_g = (ushort*)(w + off); off += (size_t)NB * NN * 2;
    ushort* rank   = (ushort*)(w + off); off += (size_t)E * 2;
    int* total    = (int*)(w + off); off += 40064;
    int* edge_src = (int*)(w + off); off += (size_t)NN * PAD * 4;
    ushort* xb    = (ushort*)(w + off); off += (size_t)NN * DIN * 2;
    ushort* w1f   = (ushort*)(w + off); off += 65536;
    ushort* w2f   = (ushort*)(w + off); off += 131072;
    ushort* h1f   = (ushort*)(w + off); off += (size_t)NN * DOUT * 2;
    ushort* h2b   = (ushort*)(w + off); off += (size_t)NN * DOUT * 2;
    float* out    = (float*)d_out;

    khist_prep<<<NB + NPREP, 256, 0, stream>>>(ei, hist_g, rank, E, x, xb,
                                               W1, w1f, W2, w2f, stats);
    kscan_a<<<40, 256, 0, stream>>>(hist_g, total);
    kfill<<<256, 256, 0, stream>>>(ei, hist_g, rank, edge_src, E);
    gemm1_k<<<NTILES, 512, 0, stream>>>(x, xb, total, edge_src, w1f, b1,
                                        h1f, sum1, sq1);
    gemm2_k<<<NTILES, 512, 0, stream>>>(h1f, sum1, sq1, gamma1, beta1, w2f,
                                        b2, h2b, sum2, sq2);
    bn_relu_out_k<<<NN * DOUT / 4 / 1024, 256, 0, stream>>>(h2b, sum2, sq2,
                                                            gamma2, beta2, out);
}